// Round 2
// baseline (254.521 us; speedup 1.0000x reference)
//
#include <hip/hip_runtime.h>
#include <stdint.h>

// WeightsDropout: per row of 4096 f32 (all > 0), drop the 2048 smallest
// (stable tie-break: smaller index dropped first), softmax over survivors.
//
// R2 design: ONE ROW PER WAVE. 64 elements/lane held in registers; all
// reductions are wave-level (__ballot + s_bcnt / __shfl_xor) -- zero
// __syncthreads, zero LDS. Threshold found by interpolation search on the
// float bit pattern (positive floats: bit order == value order), alternating
// with bisection for a worst-case log bound; early-exit when <=2 candidates
// remain in the bracket (~6 count passes typical vs 27 for pure bisection).
constexpr int N     = 4096;
constexpr int KSEL  = 2048;        // int(N * 0.5)
constexpr int BLOCK = 256;
constexpr int RPB   = BLOCK / 64;  // 4 independent rows (waves) per block
constexpr int EPT   = N / 64;      // 64 elements per lane

__global__ __launch_bounds__(BLOCK, 4)
void wdrop_kernel(const float* __restrict__ w, float* __restrict__ out) {
    const int lane = threadIdx.x & 63;
    const int wid  = threadIdx.x >> 6;
    const uint64_t row  = (uint64_t)blockIdx.x * RPB + wid;
    const uint64_t base = row * (uint64_t)N;

    // ---- load 64 elements as 16 coalesced float4s (chunk c -> float4 c*64+lane)
    uint32_t b[EPT];
    const uint4* wf = (const uint4*)(w + base);
#pragma unroll
    for (int c = 0; c < EPT / 4; ++c) {
        uint4 u = wf[c * 64 + lane];
        b[c * 4 + 0] = u.x; b[c * 4 + 1] = u.y; b[c * 4 + 2] = u.z; b[c * 4 + 3] = u.w;
    }
    // linear index of element e in lane l: ((e>>2)<<8) + (l<<2) + (e&3)

    // ---- row min/max on bits (positive floats => monotone in bits, < 2^31)
    uint32_t mn = b[0], mx = b[0];
#pragma unroll
    for (int e = 1; e < EPT; ++e) { mn = min(mn, b[e]); mx = max(mx, b[e]); }
#pragma unroll
    for (int off = 32; off > 0; off >>= 1) {
        mn = min(mn, (uint32_t)__shfl_xor((int)mn, off, 64));
        mx = max(mx, (uint32_t)__shfl_xor((int)mx, off, 64));
    }
    const uint32_t mxbits = mx;

    // ---- find T = k-th smallest bits. invariant: c_lo = count(<lo) < K <= c_hi = count(<=hi)
    uint32_t lo = mn, hi = mx;
    int c_lo = 0, c_hi = N;
    uint32_t T = 0;
    bool tie = false;      // wave-uniform
    int  tie_j = 0;
    int  iter = 0;
    for (;;) {
        const int r = c_hi - c_lo;       // candidates in [lo,hi]
        const int j = KSEL - c_lo;       // rank we need within the bracket
        if (lo == hi) { T = lo; tie = true; tie_j = j; break; }
        if (r <= 2) {
            // min/max value among in-range elements
            uint32_t mn_ir = 0xFFFFFFFFu, mx_ir = 0u;
#pragma unroll
            for (int e = 0; e < EPT; ++e) {
                if (b[e] >= lo && b[e] <= hi) {
                    mn_ir = min(mn_ir, b[e]);
                    mx_ir = max(mx_ir, b[e]);
                }
            }
#pragma unroll
            for (int off = 32; off > 0; off >>= 1) {
                mn_ir = min(mn_ir, (uint32_t)__shfl_xor((int)mn_ir, off, 64));
                mx_ir = max(mx_ir, (uint32_t)__shfl_xor((int)mx_ir, off, 64));
            }
            if (mn_ir == mx_ir) { T = mn_ir; tie = true; tie_j = j; }  // r duplicates of T
            else                { T = (j == 1) ? mn_ir : mx_ir; }      // r==2 distinct
            break;
        }
        // pivot: interpolate (uniform data => ~sqrt shrink) alternated with bisection
        uint32_t mid;
        if (iter & 1) {
            mid = lo + ((hi - lo) >> 1);
        } else {
            const float vl = __uint_as_float(lo), vh = __uint_as_float(hi);
            const float mv = vl + (vh - vl) * ((float)j / (float)(r + 1));
            mid = __float_as_uint(mv);
            mid = min(max(mid, lo), hi - 1);
        }
        int c = 0;
#pragma unroll
        for (int e = 0; e < EPT; ++e)
            c += __popcll(__ballot(b[e] <= mid));   // v_cmp + scalar bcnt, wave-uniform
        if (c >= KSEL) { hi = mid; c_hi = c; }
        else           { lo = mid + 1; c_lo = c; }
        ++iter;
    }

    // ---- rare tie path: thr_idx = j-th smallest linear index among elements == T
    int thr_idx = N;   // non-tie: equals-to-T (the k-th element itself) dropped
    if (tie) {
        int cur = -1;
        for (int q = 0; q < tie_j; ++q) {
            int cand = 0x7FFFFFFF;
#pragma unroll
            for (int e = 0; e < EPT; ++e) {
                const int idx = ((e >> 2) << 8) + (lane << 2) + (e & 3);
                if (b[e] == T && idx > cur) cand = min(cand, idx);
            }
#pragma unroll
            for (int off = 32; off > 0; off >>= 1)
                cand = min(cand, __shfl_xor(cand, off, 64));
            cur = cand;
        }
        thr_idx = cur;
    }

    // ---- keep + exp (overwrite b[] with exp bits), wave sum
    const float m = __uint_as_float(mxbits);
    float s = 0.0f;
#pragma unroll
    for (int e = 0; e < EPT; ++e) {
        const int idx = ((e >> 2) << 8) + (lane << 2) + (e & 3);
        const bool keep = (b[e] > T) || (b[e] == T && idx > thr_idx);
        const float ev = keep ? __expf(__uint_as_float(b[e]) - m) : 0.0f;
        b[e] = __float_as_uint(ev);
        s += ev;
    }
#pragma unroll
    for (int off = 32; off > 0; off >>= 1) s += __shfl_xor(s, off, 64);
    const float inv = 1.0f / s;

    // ---- scale + coalesced float4 store
    uint4* of = (uint4*)(out + base);
#pragma unroll
    for (int c = 0; c < EPT / 4; ++c) {
        float4 o;
        o.x = __uint_as_float(b[c * 4 + 0]) * inv;
        o.y = __uint_as_float(b[c * 4 + 1]) * inv;
        o.z = __uint_as_float(b[c * 4 + 2]) * inv;
        o.w = __uint_as_float(b[c * 4 + 3]) * inv;
        ((float4*)of)[c * 64 + lane] = o;
    }
}

extern "C" void kernel_launch(void* const* d_in, const int* in_sizes, int n_in,
                              void* d_out, int out_size, void* d_ws, size_t ws_size,
                              hipStream_t stream) {
    const float* w = (const float*)d_in[0];
    float* out = (float*)d_out;
    const int rows = in_sizes[0] / N;          // 8192 rows of 4096
    wdrop_kernel<<<rows / RPB, BLOCK, 0, stream>>>(w, out);
}

// Round 3
// 232.892 us; speedup vs baseline: 1.0929x; 1.0929x over previous
//
#include <hip/hip_runtime.h>
#include <stdint.h>

// WeightsDropout: per row of 4096 f32 (all in (0,1)), drop the 2048 smallest
// (stable tie-break: smaller index dropped first), softmax over survivors.
//
// R3: row per 256-thread block, 16 elems/lane in registers (VGPR-safe; R2's
// 64/lane spilled to scratch, +80 MB HBM traffic). Selection via single-pass
// bucket histogram (values uniform in (0,1) => bucket = v*1024, ~4/bucket):
// hist -> block scan -> crossing bucket -> gather ~4 candidates -> exact
// (bits,idx) lexicographic rank. 8 barriers total vs R1's 54; tie semantics
// handled uniformly by the lexicographic threshold pair.
constexpr int N     = 4096;
constexpr int KSEL  = 2048;          // int(N * 0.5)
constexpr int BLOCK = 256;
constexpr int NW    = BLOCK / 64;    // 4 waves
constexpr int EPT   = N / BLOCK;     // 16 elements / thread
constexpr int NB    = 1024;          // buckets
constexpr int CAP   = 512;           // candidate list capacity (E[r]=4)

__device__ __forceinline__ int bucket_of(uint32_t bits) {
    // positive floats; monotone non-decreasing map into [0,1023]
    int bk = (int)(__uint_as_float(bits) * 1024.0f);
    return min(bk, NB - 1);
}

__global__ __launch_bounds__(BLOCK, 4)
void wdrop_kernel(const float* __restrict__ w, float* __restrict__ out) {
    const int t    = threadIdx.x;
    const int wid  = t >> 6;
    const int lane = t & 63;
    const uint64_t base = (uint64_t)blockIdx.x * (uint64_t)N;

    __shared__ int      hist[NB];
    __shared__ int      scan_w[NW];
    __shared__ uint32_t umax[NW];
    __shared__ int      sel_b, sel_c;     // crossing bucket, count before it
    __shared__ int      cn;
    __shared__ uint32_t cbits[CAP];
    __shared__ int      cidx[CAP];
    __shared__ uint32_t thrT, thrI;
    __shared__ float    red_f[NW];

    // ---- 1. zero hist / counters
#pragma unroll
    for (int i = 0; i < NB / BLOCK; ++i) hist[t + i * BLOCK] = 0;
    if (t == 0) cn = 0;
    __syncthreads();                                          // A

    // ---- 2. load 16 elems (4 coalesced float4), histogram, thread max
    uint32_t b[EPT];
    const uint4* wf = (const uint4*)(w + base);
#pragma unroll
    for (int j = 0; j < EPT / 4; ++j) {
        uint4 u = wf[j * BLOCK + t];
        b[j * 4 + 0] = u.x; b[j * 4 + 1] = u.y; b[j * 4 + 2] = u.z; b[j * 4 + 3] = u.w;
    }
    uint32_t mx = b[0];
#pragma unroll
    for (int e = 0; e < EPT; ++e) {
        mx = max(mx, b[e]);
        atomicAdd(&hist[bucket_of(b[e])], 1);
    }
#pragma unroll
    for (int off = 32; off > 0; off >>= 1)
        mx = max(mx, (uint32_t)__shfl_xor((int)mx, off, 64));
    if (lane == 0) umax[wid] = mx;
    __syncthreads();                                          // B

    // ---- 3. row max; per-thread 4-bucket sum; block inclusive scan
    uint32_t mxbits = umax[0];
#pragma unroll
    for (int i = 1; i < NW; ++i) mxbits = max(mxbits, umax[i]);
    const int h0 = hist[4 * t + 0], h1 = hist[4 * t + 1];
    const int h2 = hist[4 * t + 2], h3 = hist[4 * t + 3];
    const int p = h0 + h1 + h2 + h3;
    int sc = p;
#pragma unroll
    for (int off = 1; off < 64; off <<= 1) {
        const int v = __shfl_up(sc, off, 64);
        if (lane >= off) sc += v;
    }
    if (lane == 63) scan_w[wid] = sc;
    __syncthreads();                                          // C

    int wbase = 0;
#pragma unroll
    for (int i = 0; i < NW; ++i) wbase += (i < wid) ? scan_w[i] : 0;
    const int inc = sc + wbase;          // inclusive prefix over 4t..4t+3
    const int exc = inc - p;
    if (exc < KSEL && KSEL <= inc) {     // exactly one thread matches
        int c = exc, bk = 4 * t;
        if      (c + h0 >= KSEL) { }
        else if (c + h0 + h1 >= KSEL)           { c += h0;          bk += 1; }
        else if (c + h0 + h1 + h2 >= KSEL)      { c += h0 + h1;     bk += 2; }
        else                                    { c += h0 + h1 + h2; bk += 3; }
        sel_b = bk; sel_c = c;
    }
    __syncthreads();                                          // D

    // ---- 4. gather candidates in the crossing bucket
    const int bstar = sel_b;
    const int j_in  = KSEL - sel_c;      // 1-based rank needed within bucket
#pragma unroll
    for (int e = 0; e < EPT; ++e) {
        if (bucket_of(b[e]) == bstar) {
            const int slot = atomicAdd(&cn, 1);
            if (slot < CAP) {
                cbits[slot] = b[e];
                cidx[slot]  = ((e >> 2) * BLOCK + t) * 4 + (e & 3);
            }
        }
    }
    __syncthreads();                                          // E

    // ---- 5. exact rank among candidates -> threshold pair (k-th smallest)
    const int r = min(cn, CAP);
    if (t < r) {
        const uint32_t myb = cbits[t];
        const int      myi = cidx[t];
        int rank = 0;
        for (int q = 0; q < r; ++q) {
            const uint32_t qb = cbits[q];
            rank += (qb < myb) || (qb == myb && cidx[q] < myi);
        }
        if (rank == j_in - 1) { thrT = myb; thrI = (uint32_t)myi; }
    }
    __syncthreads();                                          // F

    // ---- 6. keep + exp + block sum
    const uint32_t T  = thrT;
    const int      ti = (int)thrI;
    const float m = __uint_as_float(mxbits);
    float s = 0.0f;
#pragma unroll
    for (int e = 0; e < EPT; ++e) {
        const int idx = ((e >> 2) * BLOCK + t) * 4 + (e & 3);
        const bool keep = (b[e] > T) || (b[e] == T && idx > ti);
        const float ev = keep ? __expf(__uint_as_float(b[e]) - m) : 0.0f;
        b[e] = __float_as_uint(ev);
        s += ev;
    }
#pragma unroll
    for (int off = 32; off > 0; off >>= 1) s += __shfl_xor(s, off, 64);
    if (lane == 0) red_f[wid] = s;
    __syncthreads();                                          // G
    float tot = 0.0f;
#pragma unroll
    for (int i = 0; i < NW; ++i) tot += red_f[i];
    const float inv = 1.0f / tot;

    // ---- 7. scale + coalesced float4 store
    uint4* of = (uint4*)(out + base);
#pragma unroll
    for (int j = 0; j < EPT / 4; ++j) {
        float4 o;
        o.x = __uint_as_float(b[j * 4 + 0]) * inv;
        o.y = __uint_as_float(b[j * 4 + 1]) * inv;
        o.z = __uint_as_float(b[j * 4 + 2]) * inv;
        o.w = __uint_as_float(b[j * 4 + 3]) * inv;
        ((float4*)of)[j * BLOCK + t] = o;
    }
}

extern "C" void kernel_launch(void* const* d_in, const int* in_sizes, int n_in,
                              void* d_out, int out_size, void* d_ws, size_t ws_size,
                              hipStream_t stream) {
    const float* w = (const float*)d_in[0];
    float* out = (float*)d_out;
    const int rows = in_sizes[0] / N;           // 8192 rows of 4096
    wdrop_kernel<<<rows, BLOCK, 0, stream>>>(w, out);
}

// Round 4
// 232.646 us; speedup vs baseline: 1.0940x; 1.0011x over previous
//
#include <hip/hip_runtime.h>
#include <stdint.h>

// WeightsDropout: per row of 4096 f32 (uniform in (1e-4,1)), drop the 2048
// smallest (stable tie-break: smaller index dropped first), softmax survivors.
//
// R4: 2 rows per 256-thread block (barriers/scan amortized, 2x loads in
// flight). Selection: values are uniform so the k-th order statistic lies in
// [0.45,0.55) whp -> fine 256-bucket histogram over that band only (~410
// elems/row histogrammed instead of 4096; scan is 1 bucket/thread), exact
// lex-(bits,idx) rank inside the crossing bucket. Block-uniform exact
// bisection fallback (value bits, then index) guarantees correctness for any
// input; never taken for uniform data.
constexpr int N     = 4096;
constexpr int KSEL  = 2048;          // int(N * 0.5)
constexpr int BLOCK = 256;
constexpr int NW    = BLOCK / 64;    // 4 waves
constexpr int EPT   = N / BLOCK;     // 16 elements/thread/row
constexpr int RPB   = 2;             // rows per block
constexpr int NB    = 256;           // fine buckets over the band
constexpr int CAP   = 128;           // candidate capacity (E[#]=1.6)
constexpr float P1  = 0.45f;
constexpr float P2  = 0.55f;
constexpr float BSCALE = 2560.0f;    // NB / (P2 - P1)

__global__ __launch_bounds__(BLOCK, 4)
void wdrop_kernel(const float* __restrict__ w, float* __restrict__ out) {
    const int t = threadIdx.x, wid = t >> 6, lane = t & 63;
    const uint64_t row0 = (uint64_t)blockIdx.x * RPB;

    __shared__ int      hist[RPB][NB];
    __shared__ uint32_t redu[RPB][NW];
    __shared__ int      redi[RPB][NW];
    __shared__ float    redf[RPB][NW];
    __shared__ int      scanw[RPB][NW];
    __shared__ int      selb[RPB], selc[RPB];
    __shared__ int      cn[RPB];
    __shared__ uint32_t cb[RPB][CAP];
    __shared__ int      ci[RPB][CAP];
    __shared__ uint32_t thrT[RPB], thrI[RPB];

    // ---- issue all 8 float4 loads up front (MLP), then zero LDS while in flight
    uint32_t v[RPB][EPT];
    {
        const uint4* wf0 = (const uint4*)(w + row0 * N);
        const uint4* wf1 = (const uint4*)(w + (row0 + 1) * N);
        uint4 u0[EPT / 4], u1[EPT / 4];
#pragma unroll
        for (int j = 0; j < EPT / 4; ++j) u0[j] = wf0[j * BLOCK + t];
#pragma unroll
        for (int j = 0; j < EPT / 4; ++j) u1[j] = wf1[j * BLOCK + t];
#pragma unroll
        for (int j = 0; j < EPT / 4; ++j) {
            v[0][j*4+0]=u0[j].x; v[0][j*4+1]=u0[j].y; v[0][j*4+2]=u0[j].z; v[0][j*4+3]=u0[j].w;
            v[1][j*4+0]=u1[j].x; v[1][j*4+1]=u1[j].y; v[1][j*4+2]=u1[j].z; v[1][j*4+3]=u1[j].w;
        }
    }
    hist[0][t] = 0; hist[1][t] = 0;
    if (t < RPB) cn[t] = 0;

    // ---- per-row max + band counts (clo = #(<P1), chi = #(<P2)), packed reduce
#pragma unroll
    for (int r = 0; r < RPB; ++r) {
        uint32_t mx = v[r][0];
        int clo = 0, chi = 0;
#pragma unroll
        for (int e = 0; e < EPT; ++e) {
            mx = max(mx, v[r][e]);
            const float f = __uint_as_float(v[r][e]);
            clo += (f < P1); chi += (f < P2);
        }
        int pk = (clo << 16) | chi;     // fields stay < 4096: no carry
#pragma unroll
        for (int off = 32; off > 0; off >>= 1) {
            mx = max(mx, (uint32_t)__shfl_xor((int)mx, off, 64));
            pk += __shfl_xor(pk, off, 64);
        }
        if (lane == 0) { redu[r][wid] = mx; redi[r][wid] = pk; }
    }
    __syncthreads();                                          // B (also covers hist zeroing)

    uint32_t mxb[RPB]; int jrank[RPB]; bool fast[RPB];
#pragma unroll
    for (int r = 0; r < RPB; ++r) {
        uint32_t m = redu[r][0]; int pk = redi[r][0];
#pragma unroll
        for (int i = 1; i < NW; ++i) { m = max(m, redu[r][i]); pk += redi[r][i]; }
        const int clo = pk >> 16, chi = pk & 0xFFFF;
        mxb[r] = m;
        fast[r]  = (clo < KSEL) && (chi >= KSEL);   // k-th value in [P1,P2)
        jrank[r] = KSEL - clo;                       // rank needed within band
    }

    // ---- band histogram (only ~10% of elements)
#pragma unroll
    for (int r = 0; r < RPB; ++r) {
        if (fast[r]) {
#pragma unroll
            for (int e = 0; e < EPT; ++e) {
                const float f = __uint_as_float(v[r][e]);
                if (f >= P1 && f < P2) {
                    const int bk = min((int)((f - P1) * BSCALE), NB - 1);
                    atomicAdd(&hist[r][bk], 1);
                }
            }
        }
    }
    __syncthreads();                                          // C

    // ---- scan: one bucket per thread, both rows in lockstep
    const int h0 = hist[0][t], h1 = hist[1][t];
    int s0 = h0, s1 = h1;
#pragma unroll
    for (int off = 1; off < 64; off <<= 1) {
        const int u0 = __shfl_up(s0, off, 64);
        const int u1 = __shfl_up(s1, off, 64);
        if (lane >= off) { s0 += u0; s1 += u1; }
    }
    if (lane == 63) { scanw[0][wid] = s0; scanw[1][wid] = s1; }
    __syncthreads();                                          // D
    int wb0 = 0, wb1 = 0;
#pragma unroll
    for (int i = 0; i < NW; ++i)
        if (i < wid) { wb0 += scanw[0][i]; wb1 += scanw[1][i]; }
    const int inc0 = s0 + wb0, exc0 = inc0 - h0;
    const int inc1 = s1 + wb1, exc1 = inc1 - h1;
    if (fast[0] && exc0 < jrank[0] && jrank[0] <= inc0) { selb[0] = t; selc[0] = exc0; }
    if (fast[1] && exc1 < jrank[1] && jrank[1] <= inc1) { selb[1] = t; selc[1] = exc1; }
    __syncthreads();                                          // E

    // ---- gather candidates in crossing bucket
#pragma unroll
    for (int r = 0; r < RPB; ++r) {
        if (fast[r]) {
            const int bs = selb[r];
#pragma unroll
            for (int e = 0; e < EPT; ++e) {
                const float f = __uint_as_float(v[r][e]);
                if (f >= P1 && f < P2 && min((int)((f - P1) * BSCALE), NB - 1) == bs) {
                    const int slot = atomicAdd(&cn[r], 1);
                    if (slot < CAP) {
                        cb[r][slot] = v[r][e];
                        ci[r][slot] = ((e >> 2) * BLOCK + t) * 4 + (e & 3);
                    }
                }
            }
        }
    }
    __syncthreads();                                          // F
#pragma unroll
    for (int r = 0; r < RPB; ++r) fast[r] = fast[r] && (cn[r] <= CAP);

    // ---- exact lex rank among candidates -> (T, thrIdx) = k-th smallest pair
#pragma unroll
    for (int r = 0; r < RPB; ++r) {
        if (fast[r] && t < cn[r]) {
            const uint32_t myb = cb[r][t]; const int myi = ci[r][t];
            int rank = 0;
            for (int q = 0; q < cn[r]; ++q)
                rank += (cb[r][q] < myb) || (cb[r][q] == myb && ci[r][q] < myi);
            if (rank == jrank[r] - selc[r] - 1) { thrT[r] = myb; thrI[r] = (uint32_t)myi; }
        }
    }
    __syncthreads();                                          // G

    // ---- exact fallback (block-uniform; never taken for uniform data)
    for (int r = 0; r < RPB; ++r) {
        if (!fast[r]) {
            uint32_t blo = 0u, bhi = 0x7f7fffffu;
            while (blo < bhi) {
                const uint32_t mid = blo + ((bhi - blo) >> 1);
                int c = 0;
#pragma unroll
                for (int e = 0; e < EPT; ++e) c += __popcll(__ballot(v[r][e] <= mid));
                __syncthreads();
                if (lane == 0) redi[r][wid] = c;
                __syncthreads();
                int tot = 0;
#pragma unroll
                for (int i = 0; i < NW; ++i) tot += redi[r][i];
                if (tot >= KSEL) bhi = mid; else blo = mid + 1;
            }
            const uint32_t T = blo;
            int c = 0;
#pragma unroll
            for (int e = 0; e < EPT; ++e) c += __popcll(__ballot(v[r][e] < T));
            __syncthreads();
            if (lane == 0) redi[r][wid] = c;
            __syncthreads();
            int clt = 0;
#pragma unroll
            for (int i = 0; i < NW; ++i) clt += redi[r][i];
            const int need = KSEL - clt;
            int ilo = 0, ihi = N - 1;
            while (ilo < ihi) {
                const int imid = (ilo + ihi) >> 1;
                int cc = 0;
#pragma unroll
                for (int e = 0; e < EPT; ++e) {
                    const int idx = ((e >> 2) * BLOCK + t) * 4 + (e & 3);
                    cc += __popcll(__ballot(v[r][e] == T && idx <= imid));
                }
                __syncthreads();
                if (lane == 0) redi[r][wid] = cc;
                __syncthreads();
                int tot = 0;
#pragma unroll
                for (int i = 0; i < NW; ++i) tot += redi[r][i];
                if (tot >= need) ihi = imid; else ilo = imid + 1;
            }
            if (t == 0) { thrT[r] = T; thrI[r] = (uint32_t)ilo; }
            __syncthreads();
        }
    }

    // ---- keep + exp + block sum (both rows), then scale + store
    float s[RPB];
#pragma unroll
    for (int r = 0; r < RPB; ++r) {
        const uint32_t T = thrT[r]; const int ti = (int)thrI[r];
        const float m = __uint_as_float(mxb[r]);
        float acc = 0.0f;
#pragma unroll
        for (int e = 0; e < EPT; ++e) {
            const int idx = ((e >> 2) * BLOCK + t) * 4 + (e & 3);
            const bool keep = (v[r][e] > T) || (v[r][e] == T && idx > ti);
            const float ev = keep ? __expf(__uint_as_float(v[r][e]) - m) : 0.0f;
            v[r][e] = __float_as_uint(ev);
            acc += ev;
        }
#pragma unroll
        for (int off = 32; off > 0; off >>= 1) acc += __shfl_xor(acc, off, 64);
        if (lane == 0) redf[r][wid] = acc;
        s[r] = 0.0f;
    }
    __syncthreads();                                          // H
#pragma unroll
    for (int r = 0; r < RPB; ++r) {
#pragma unroll
        for (int i = 0; i < NW; ++i) s[r] += redf[r][i];
        s[r] = 1.0f / s[r];
    }
#pragma unroll
    for (int r = 0; r < RPB; ++r) {
        uint4* of = (uint4*)(out + (row0 + r) * N);
#pragma unroll
        for (int j = 0; j < EPT / 4; ++j) {
            float4 o;
            o.x = __uint_as_float(v[r][j*4+0]) * s[r];
            o.y = __uint_as_float(v[r][j*4+1]) * s[r];
            o.z = __uint_as_float(v[r][j*4+2]) * s[r];
            o.w = __uint_as_float(v[r][j*4+3]) * s[r];
            ((float4*)of)[j * BLOCK + t] = o;
        }
    }
}

extern "C" void kernel_launch(void* const* d_in, const int* in_sizes, int n_in,
                              void* d_out, int out_size, void* d_ws, size_t ws_size,
                              hipStream_t stream) {
    const float* w = (const float*)d_in[0];
    float* out = (float*)d_out;
    const int rows = in_sizes[0] / N;            // 8192
    wdrop_kernel<<<rows / RPB, BLOCK, 0, stream>>>(w, out);
}